// Round 9
// baseline (68.703 us; speedup 1.0000x reference)
//
#include <hip/hip_runtime.h>
#include <math.h>

#define NCC 80
#define TOPKK 13
#define BB 16
#define NAA 8400
#define NMX 64
#define NROW (BB * NMX)        // 1024
#define NBA  (BB * NAA)        // 134400
#define RCAP 1024              // per-row candidate capacity (worst realistic ~650)
#define RPAD 16                // rcount padded to one counter per 64B line
#define PDEPTH 5               // 4 list cands (RCAP/256) + 1 injected
#define PSTR 6                 // + sentinel slot
#define JZ 4                   // j-loop split across blockIdx.z
#define JPB (NMX / JZ)         // 16 gt rows per z-slice
#define SENT 0x7fffffff
#define EPSF 1e-9f
#define IOUEPS 1e-7f
#define INV_PI2 0.4052847345693511f

__device__ __forceinline__ float ciou2(float gx1, float gy1, float gx2, float gy2,
                                       float gw, float gh, float gat,
                                       float px1, float py1, float px2, float py2,
                                       float pat)
{
    float w2 = px2 - px1, h2 = py2 - py1;
    float iw = fmaxf(fminf(gx2, px2) - fmaxf(gx1, px1), 0.f);
    float ih = fmaxf(fminf(gy2, py2) - fmaxf(gy1, py1), 0.f);
    float inter = iw * ih;
    float uni = gw * gh + w2 * h2 - inter + IOUEPS;
    float iou = inter / uni;
    float cw = fmaxf(gx2, px2) - fminf(gx1, px1);
    float ch = fmaxf(gy2, py2) - fminf(gy1, py1);
    float c2 = cw * cw + ch * ch + IOUEPS;
    float dx = px1 + px2 - gx1 - gx2;
    float dy = py1 + py2 - gy1 - gy2;
    float rho2 = (dx * dx + dy * dy) * 0.25f;
    float da = pat - gat;
    float v = INV_PI2 * da * da;
    float alpha = v / (v - iou + (1.f + IOUEPS));
    return iou - (rho2 / c2 + v * alpha);
}

// KZ: zero padded rcount (the one array KP mutates with atomics).
__global__ __launch_bounds__(256) void kz_zero(int* __restrict__ rcount)
{
    int i = blockIdx.x * 256 + threadIdx.x;
    if (i < NROW * RPAD) rcount[i] = 0;
}

// KP: anchor-major scan, wave-aggregated appends (unchanged from R7).
__global__ __launch_bounds__(256) void kp_scan(
    const float* __restrict__ anc,
    const float* __restrict__ gt_bboxes,
    const float* __restrict__ mask_gt,
    int* __restrict__ cnt, int* __restrict__ pos,
    int* __restrict__ rcount, int* __restrict__ rlist)
{
    const int tid = threadIdx.x;
    const int lane = tid & 63;
    const int b = blockIdx.y;
    const int jz = blockIdx.z;
    const int a = blockIdx.x * 256 + tid;
    const bool valid = a < NAA;

    __shared__ float4 glds[JPB];
    __shared__ float  mlds[JPB];
    if (tid < JPB) {
        glds[tid] = reinterpret_cast<const float4*>(gt_bboxes)[b * NMX + jz * JPB + tid];
        mlds[tid] = mask_gt[b * NMX + jz * JPB + tid];
    }
    if (jz == 0 && b == 0 && blockIdx.x < 8) pos[blockIdx.x * 256 + tid] = 0;
    __syncthreads();

    float2 ap = valid ? reinterpret_cast<const float2*>(anc)[a]
                      : make_float2(-1e9f, -1e9f);
    if (jz == 0 && valid) cnt[b * NAA + a] = 0;

    for (int jj = 0; jj < JPB; ++jj) {
        const int j = jz * JPB + jj;
        float4 g = glds[jj];
        float din = fminf(fminf(ap.x - g.x, ap.y - g.y), fminf(g.z - ap.x, g.w - ap.y));
        bool take = valid && (din > EPSF) && (mlds[jj] > 0.f);
        unsigned long long m = __ballot(take);
        if (m) {
            int base = 0;
            int c = __popcll(m);
            if (lane == 0) base = atomicAdd(&rcount[(b * NMX + j) * RPAD], c);
            base = __shfl(base, 0, 64);
            if (take) {
                int p = base + __popcll(m & ((1ull << lane) - 1ull));
                if (p < RCAP) rlist[(size_t)(b * NMX + j) * RCAP + p] = a;
            }
        }
    }
}

// K1: one block per (b,j) row. Candidates precompacted in rlist; inject
// {0..12}\{in-gt} (value 0) so top-13 == full-row lax.top_k exactly.
// Merge: stage 1 = per-wave 13-round shfl tournament (no barriers);
// ONE __syncthreads; stage 2 = wave 0 merges the 52 candidates and
// scatters winners. Sentinel (-1, SENT) never advances head pointers
// (fix for R8 crash: whole-wave-exhausted waves drove p past the
// sentinel slot -> OOB LDS -> bogus dupes -> pool exhaustion -> OOB
// global read via fi=SENT).
__global__ __launch_bounds__(256) void k1_topk(
    const float* __restrict__ pd_scores,
    const float* __restrict__ pd_bboxes,
    const float* __restrict__ anc,
    const int*   __restrict__ gt_labels,
    const float* __restrict__ gt_bboxes,
    const float* __restrict__ mask_gt,
    const int* __restrict__ rcount, const int* __restrict__ rlist,
    int* __restrict__ cnt)
{
    const int row = blockIdx.x;
    if (mask_gt[row] <= 0.f) return;
    const int b = row >> 6, j = row & 63;
    const int tid = threadIdx.x;
    const int lane = tid & 63, wid = tid >> 6;

    const float4 g = reinterpret_cast<const float4*>(gt_bboxes)[row];
    const float gw = g.z - g.x, gh = g.w - g.y;
    const float gat = atanf(gw / gh);
    const int gl = gt_labels[row];
    const float* sc = pd_scores + (size_t)b * NAA * NCC + gl;
    const float4* pb = reinterpret_cast<const float4*>(pd_bboxes) + (size_t)b * NAA;
    const float2* ap2 = reinterpret_cast<const float2*>(anc);

    __shared__ float cV[64];
    __shared__ int   cI[64];
    __shared__ float Lv[256 * PSTR];
    __shared__ int   Li[256 * PSTR];

    int nc = rcount[row * RPAD]; if (nc > RCAP) nc = RCAP;

    float lv[PDEPTH]; int li[PDEPTH];
#pragma unroll
    for (int k = 0; k < PDEPTH; k++) { lv[k] = -1.f; li[k] = SENT; }

#define INSERT(AL, A)                                                            \
    if ((AL) > lv[PDEPTH - 1] || ((AL) == lv[PDEPTH - 1] && (A) < li[PDEPTH - 1])) { \
        lv[PDEPTH - 1] = (AL); li[PDEPTH - 1] = (A);                             \
        _Pragma("unroll")                                                        \
        for (int k = PDEPTH - 1; k > 0; --k) {                                   \
            if (lv[k] > lv[k - 1] || (lv[k] == lv[k - 1] && li[k] < li[k - 1])) {\
                float tv = lv[k]; lv[k] = lv[k - 1]; lv[k - 1] = tv;             \
                int ti = li[k]; li[k] = li[k - 1]; li[k - 1] = ti;               \
            } else break;                                                        \
        }                                                                        \
    }

    // injected candidates: a = tid < 13, only if NOT in-gt (else already listed)
    if (tid < TOPKK) {
        float2 ap = ap2[tid];
        float din = fminf(fminf(ap.x - g.x, ap.y - g.y), fminf(g.z - ap.x, g.w - ap.y));
        if (!(din > EPSF)) { INSERT(0.f, tid); }
    }
    // list candidates (din > EPS && mask guaranteed by KP); each anchor is
    // processed by exactly ONE thread -> all candidate indices are distinct.
    for (int t = tid; t < nc; t += 256) {
        int a = rlist[(size_t)row * RCAP + t];
        float4 p = pb[a];
        float pat = atanf((p.z - p.x) / (p.w - p.y));
        float c = ciou2(g.x, g.y, g.z, g.w, gw, gh, gat, p.x, p.y, p.z, p.w, pat);
        float o = fmaxf(c, 0.f);
        float o2 = o * o;
        float al = sc[(size_t)a * NCC] * (o2 * o2 * o2);
        INSERT(al, a);
    }
#undef INSERT

    // spill sorted lists to LDS (dynamic head index); same-wave DS ops are
    // pipeline-ordered, so stage 1 needs no block barrier.
#pragma unroll
    for (int k = 0; k < PDEPTH; k++) { Lv[tid * PSTR + k] = lv[k]; Li[tid * PSTR + k] = li[k]; }
    Lv[tid * PSTR + PDEPTH] = -1.f;            // sentinel (exhausted head)
    Li[tid * PSTR + PDEPTH] = SENT;

    // ---- stage 1: per-wave 13-round shfl tournament (no barriers) ----
    int p = 0;
    float myv = -1.f; int myi = SENT;
    for (int r = 0; r < TOPKK; ++r) {
        float hv = Lv[tid * PSTR + p];
        int   hi = Li[tid * PSTR + p];
        float wv = hv; int wi = hi;
#pragma unroll
        for (int s = 1; s < 64; s <<= 1) {
            float ov = __shfl_xor(wv, s, 64);
            int   oi = __shfl_xor(wi, s, 64);
            if (ov > wv || (ov == wv && oi < wi)) { wv = ov; wi = oi; }
        }
        if (lane == r) { myv = wv; myi = wi; }
        if (hi == wi && wi != SENT) ++p;        // real win only -> p <= PDEPTH
    }
    if (lane < TOPKK) { cV[wid * TOPKK + lane] = myv; cI[wid * TOPKK + lane] = myi; }
    __syncthreads();                            // the ONLY block barrier

    // ---- stage 2: wave 0 merges 52 candidates, scatters winners ----
    if (wid == 0) {
        float v = (lane < 4 * TOPKK) ? cV[lane] : -2.f;
        int   i = (lane < 4 * TOPKK) ? cI[lane] : SENT;
        float fv = -1.f; int fi = SENT;
        for (int r = 0; r < TOPKK; ++r) {
            float wv = v; int wi = i;
#pragma unroll
            for (int s = 1; s < 64; s <<= 1) {
                float ov = __shfl_xor(wv, s, 64);
                int   oi = __shfl_xor(wi, s, 64);
                if (ov > wv || (ov == wv && oi < wi)) { wv = ov; wi = oi; }
            }
            if (lane == r) { fv = wv; fi = wi; }
            if (i == wi && wi != SENT) v = -2.f;  // consume real winner only
        }
        if (lane < TOPKK && fi >= 0 && fi < NAA) {
            int a = fi;
            float2 ap = ap2[a];
            float din = fminf(fminf(ap.x - g.x, ap.y - g.y), fminf(g.z - ap.x, g.w - ap.y));
            if (din > EPSF)
                atomicAdd(&cnt[(size_t)b * NAA + a], 1 + (j << 8));
        }
    }
}

// K2: per-anchor multi-gt resolution + per-row pos_align/pos_ovl maxima.
__global__ __launch_bounds__(256) void k2_resolve(
    const float* __restrict__ pd_scores,
    const float* __restrict__ pd_bboxes,
    const float* __restrict__ anc,
    const int*   __restrict__ gt_labels,
    const float* __restrict__ gt_bboxes,
    const float* __restrict__ mask_gt,
    const int* __restrict__ cnt,
    int* __restrict__ tgt, int* __restrict__ fgm, float* __restrict__ alv,
    int* __restrict__ pos)
{
    const int id = blockIdx.x * 256 + threadIdx.x;
    const int b = id / NAA;
    const int a = id - b * NAA;
    const int v = cnt[id];
    const int fg = v & 0xff;
    int tj = 0, f = 0;
    float al = 0.f;
    if (fg > 0) {
        f = 1;
        float2 ap = reinterpret_cast<const float2*>(anc)[a];
        float4 p = reinterpret_cast<const float4*>(pd_bboxes)[id];
        float pat = atanf((p.z - p.x) / (p.w - p.y));
        if (fg == 1) {
            tj = v >> 8;
        } else {
            float bv = -1.f; int bj = 0;
            for (int jj = 0; jj < NMX; ++jj) {
                float4 g = reinterpret_cast<const float4*>(gt_bboxes)[b * NMX + jj];
                float din = fminf(fminf(ap.x - g.x, ap.y - g.y), fminf(g.z - ap.x, g.w - ap.y));
                float ov = 0.f;
                if (din > EPSF && mask_gt[b * NMX + jj] > 0.f) {
                    float gw = g.z - g.x, gh = g.w - g.y;
                    float c = ciou2(g.x, g.y, g.z, g.w, gw, gh, atanf(gw / gh),
                                    p.x, p.y, p.z, p.w, pat);
                    ov = fmaxf(c, 0.f);
                }
                if (ov > bv) { bv = ov; bj = jj; }   // strict > == first-argmax
            }
            tj = bj;
        }
        float4 g = reinterpret_cast<const float4*>(gt_bboxes)[b * NMX + tj];
        float din = fminf(fminf(ap.x - g.x, ap.y - g.y), fminf(g.z - ap.x, g.w - ap.y));
        if (din > EPSF && mask_gt[b * NMX + tj] > 0.f) {
            float gw = g.z - g.x, gh = g.w - g.y;
            float c = ciou2(g.x, g.y, g.z, g.w, gw, gh, atanf(gw / gh),
                            p.x, p.y, p.z, p.w, pat);
            float ov = fmaxf(c, 0.f);
            int gl = gt_labels[b * NMX + tj];
            float s = pd_scores[(size_t)id * NCC + gl];
            float o2 = ov * ov;
            al = s * (o2 * o2 * o2);
            if (ov > 0.f)
                atomicMax((unsigned int*)&pos[NROW + b * NMX + tj], __float_as_uint(ov));
        }
        if (al > 0.f)
            atomicMax((unsigned int*)&pos[b * NMX + tj], __float_as_uint(al));
    }
    tgt[id] = tj; fgm[id] = f; alv[id] = al;
}

// K3: all outputs, fully written; score region via coalesced float4 stores.
__global__ __launch_bounds__(256) void k3_out(
    const int* __restrict__ gt_labels,
    const float* __restrict__ gt_bboxes,
    const int* __restrict__ tgt, const int* __restrict__ fgm,
    const float* __restrict__ alv, const int* __restrict__ pos,
    float* __restrict__ o_lab, float* __restrict__ o_box, float* __restrict__ o_sc,
    float* __restrict__ o_fg, float* __restrict__ o_ti)
{
    const int id0 = blockIdx.x * 256;
    const int tid = threadIdx.x;
    const int id = id0 + tid;
    const int b = id / NAA;
    const int tj = tgt[id];
    const int f = fgm[id];
    int lab = gt_labels[b * NMX + tj]; lab = lab < 0 ? 0 : lab;
    float4 gb = reinterpret_cast<const float4*>(gt_bboxes)[b * NMX + tj];
    o_lab[id] = (float)lab;
    reinterpret_cast<float4*>(o_box)[id] = gb;
    o_fg[id] = f ? 1.f : 0.f;
    o_ti[id] = (float)tj;
    float val = 0.f;
    if (f) {
        float pa = __uint_as_float((unsigned int)pos[b * NMX + tj]);
        float po = __uint_as_float((unsigned int)pos[NROW + b * NMX + tj]);
        val = (alv[id] * po) / (pa + EPSF);
    }
    __shared__ int   s_lab[256];
    __shared__ float s_val[256];
    s_lab[tid] = lab;
    s_val[tid] = val;
    __syncthreads();
    float4* dst = reinterpret_cast<float4*>(o_sc + (size_t)id0 * NCC);
    const int NV = 256 * NCC / 4;   // 5120 float4s per block
#pragma unroll 4
    for (int i = tid; i < NV; i += 256) {
        int aa = i / (NCC / 4);
        int c0 = (i - aa * (NCC / 4)) * 4;
        int la = s_lab[aa];
        float vv = s_val[aa];
        float4 w;
        w.x = (la == c0 + 0) ? vv : 0.f;
        w.y = (la == c0 + 1) ? vv : 0.f;
        w.z = (la == c0 + 2) ? vv : 0.f;
        w.w = (la == c0 + 3) ? vv : 0.f;
        dst[i] = w;
    }
}

extern "C" void kernel_launch(void* const* d_in, const int* in_sizes, int n_in,
                              void* d_out, int out_size, void* d_ws, size_t ws_size,
                              hipStream_t stream)
{
    const float* pd_scores = (const float*)d_in[0];
    const float* pd_bboxes = (const float*)d_in[1];
    const float* anc       = (const float*)d_in[2];
    // d_in[3] rfields: unused by the reference
    const int*   gt_labels = (const int*)d_in[4];
    const float* gt_bboxes = (const float*)d_in[5];
    const float* mask_gt   = (const float*)d_in[6];

    const size_t nba = (size_t)NBA;
    int* cnt    = (int*)d_ws;                    // NBA
    int* pos    = cnt + nba;                     // 2*NROW (pos_al | pos_ov)
    int* rcount = pos + 2 * NROW;                // NROW*RPAD
    int* rlist  = rcount + (size_t)NROW * RPAD;  // NROW*RCAP
    int* tgt    = rlist + (size_t)NROW * RCAP;   // NBA
    int* fgm    = tgt + nba;                     // NBA
    float* alv  = (float*)(fgm + nba);           // NBA

    float* out = (float*)d_out;
    float* o_lab = out;                 // (B,NA)
    float* o_box = out + nba;           // (B,NA,4)
    float* o_sc  = out + nba * 5;       // (B,NA,NC)
    float* o_fg  = out + nba * 85;      // (B,NA)
    float* o_ti  = out + nba * 86;      // (B,NA)

    kz_zero<<<(NROW * RPAD + 255) / 256, 256, 0, stream>>>(rcount);
    kp_scan<<<dim3((NAA + 255) / 256, BB, JZ), 256, 0, stream>>>(
        anc, gt_bboxes, mask_gt, cnt, pos, rcount, rlist);
    k1_topk<<<NROW, 256, 0, stream>>>(pd_scores, pd_bboxes, anc, gt_labels,
                                      gt_bboxes, mask_gt, rcount, rlist, cnt);
    const int nblk = NBA / 256;   // 525, exact
    k2_resolve<<<nblk, 256, 0, stream>>>(pd_scores, pd_bboxes, anc, gt_labels,
                                         gt_bboxes, mask_gt, cnt,
                                         tgt, fgm, alv, pos);
    k3_out<<<nblk, 256, 0, stream>>>(gt_labels, gt_bboxes, tgt, fgm, alv, pos,
                                     o_lab, o_box, o_sc, o_fg, o_ti);
}

// Round 10
// 63.719 us; speedup vs baseline: 1.0782x; 1.0782x over previous
//
#include <hip/hip_runtime.h>
#include <math.h>

#define NCC 80
#define TOPKK 13
#define BB 16
#define NAA 8400
#define NMX 64
#define NROW (BB * NMX)        // 1024
#define NBA  (BB * NAA)        // 134400
#define LCAP 1024              // compacted candidates (worst realistic ~660)
#define PDEPTH 4               // ceil(LCAP/256): lossless per-thread depth
#define PSTR 5                 // + sentinel slot
#define SENT 0x7fffffff
#define NZI (NBA + 2 * NROW)   // cnt | pos zero region, 136448 ints
#define NZI4 (NZI / 4)         // 34112
#define EPSF 1e-9f
#define IOUEPS 1e-7f
#define INV_PI2 0.4052847345693511f

__device__ __forceinline__ float ciou2(float gx1, float gy1, float gx2, float gy2,
                                       float gw, float gh, float gat,
                                       float px1, float py1, float px2, float py2,
                                       float pat)
{
    float w2 = px2 - px1, h2 = py2 - py1;
    float iw = fmaxf(fminf(gx2, px2) - fmaxf(gx1, px1), 0.f);
    float ih = fmaxf(fminf(gy2, py2) - fmaxf(gy1, py1), 0.f);
    float inter = iw * ih;
    float uni = gw * gh + w2 * h2 - inter + IOUEPS;
    float iou = inter / uni;
    float cw = fmaxf(gx2, px2) - fminf(gx1, px1);
    float ch = fmaxf(gy2, py2) - fminf(gy1, py1);
    float c2 = cw * cw + ch * ch + IOUEPS;
    float dx = px1 + px2 - gx1 - gx2;
    float dy = py1 + py2 - gy1 - gy2;
    float rho2 = (dx * dx + dy * dy) * 0.25f;
    float da = pat - gat;
    float v = INV_PI2 * da * da;
    float alpha = v / (v - iou + (1.f + IOUEPS));
    return iou - (rho2 / c2 + v * alpha);
}

// KZ: zero cnt | pos (contiguous).
__global__ __launch_bounds__(256) void kz_zero(int4* __restrict__ z)
{
    int i = blockIdx.x * 256 + threadIdx.x;
    if (i < NZI4) z[i] = make_int4(0, 0, 0, 0);
}

// KA: fused scan + top-13 per gt row (R5's measured-fast structure + light merge).
// Pass 1: ballot-compact S = {in-gt} U {0..12} into LDS (exact top-13 of the
//         full row is provably inside S). Pass 2: align_metric on S, per-thread
//         sorted depth-4 lists (lossless: <=4 candidates/thread). Merge:
//         per-wave 13-round shfl tournament (sentinel-guarded), ONE barrier,
//         wave-0 merges 52 candidates and scatters packed count|jsum into cnt.
__global__ __launch_bounds__(256) void ka_topk(
    const float* __restrict__ pd_scores,
    const float* __restrict__ pd_bboxes,
    const float* __restrict__ anc,
    const int*   __restrict__ gt_labels,
    const float* __restrict__ gt_bboxes,
    const float* __restrict__ mask_gt,
    int* __restrict__ cnt)
{
    const int row = blockIdx.x;
    if (mask_gt[row] <= 0.f) return;
    const int b = row >> 6, j = row & 63;
    const int tid = threadIdx.x;
    const int lane = tid & 63, wid = tid >> 6;

    const float4 g = reinterpret_cast<const float4*>(gt_bboxes)[row];
    const float gw = g.z - g.x, gh = g.w - g.y;
    const float gat = atanf(gw / gh);
    const int gl = gt_labels[row];
    const float* sc = pd_scores + (size_t)b * NAA * NCC + gl;
    const float4* pb = reinterpret_cast<const float4*>(pd_bboxes) + (size_t)b * NAA;
    const float2* ap2 = reinterpret_cast<const float2*>(anc);

    __shared__ int   list[LCAP];
    __shared__ int   nlist;
    __shared__ float cV[64];
    __shared__ int   cI[64];
    __shared__ float Lv[256 * PSTR];
    __shared__ int   Li[256 * PSTR];

    if (tid == 0) nlist = 0;
    __syncthreads();

    // ---- pass 1: compact candidate set ----
    for (int a = tid; a < NAA; a += 256) {
        float2 ap = ap2[a];
        float din = fminf(fminf(ap.x - g.x, ap.y - g.y), fminf(g.z - ap.x, g.w - ap.y));
        bool take = (din > EPSF) || (a < TOPKK);
        unsigned long long m = __ballot(take);
        if (m) {
            int base = 0;
            int wcnt = __popcll(m);
            if (lane == 0) base = atomicAdd(&nlist, wcnt);
            base = __shfl(base, 0, 64);
            if (take) {
                int p = base + __popcll(m & ((1ull << lane) - 1ull));
                if (p < LCAP) list[p] = a;
            }
        }
    }
    __syncthreads();
    int nc = nlist; if (nc > LCAP) nc = LCAP;

    // ---- pass 2: align_metric on candidates, per-thread sorted list ----
    float lv[PDEPTH]; int li[PDEPTH];
#pragma unroll
    for (int k = 0; k < PDEPTH; k++) { lv[k] = -1.f; li[k] = SENT; }

    for (int t = tid; t < nc; t += 256) {
        int a = list[t];
        float al = 0.f;
        float2 ap = ap2[a];
        float din = fminf(fminf(ap.x - g.x, ap.y - g.y), fminf(g.z - ap.x, g.w - ap.y));
        if (din > EPSF) {
            float4 p = pb[a];
            float pat = atanf((p.z - p.x) / (p.w - p.y));
            float c = ciou2(g.x, g.y, g.z, g.w, gw, gh, gat, p.x, p.y, p.z, p.w, pat);
            float o = fmaxf(c, 0.f);
            float o2 = o * o;
            al = sc[(size_t)a * NCC] * (o2 * o2 * o2);
        }
        if (al > lv[PDEPTH - 1] || (al == lv[PDEPTH - 1] && a < li[PDEPTH - 1])) {
            lv[PDEPTH - 1] = al; li[PDEPTH - 1] = a;
#pragma unroll
            for (int k = PDEPTH - 1; k > 0; --k) {
                if (lv[k] > lv[k - 1] || (lv[k] == lv[k - 1] && li[k] < li[k - 1])) {
                    float tv = lv[k]; lv[k] = lv[k - 1]; lv[k - 1] = tv;
                    int ti = li[k]; li[k] = li[k - 1]; li[k - 1] = ti;
                } else break;
            }
        }
    }

    // spill lists (dynamic head index); same-wave DS ops are pipeline-ordered.
#pragma unroll
    for (int k = 0; k < PDEPTH; k++) { Lv[tid * PSTR + k] = lv[k]; Li[tid * PSTR + k] = li[k]; }
    Lv[tid * PSTR + PDEPTH] = -1.f;            // sentinel (exhausted head)
    Li[tid * PSTR + PDEPTH] = SENT;

    // ---- stage 1: per-wave 13-round shfl tournament (no barriers) ----
    int p = 0;
    float myv = -1.f; int myi = SENT;
    for (int r = 0; r < TOPKK; ++r) {
        float hv = Lv[tid * PSTR + p];
        int   hi = Li[tid * PSTR + p];
        float wv = hv; int wi = hi;
#pragma unroll
        for (int s = 1; s < 64; s <<= 1) {
            float ov = __shfl_xor(wv, s, 64);
            int   oi = __shfl_xor(wi, s, 64);
            if (ov > wv || (ov == wv && oi < wi)) { wv = ov; wi = oi; }
        }
        if (lane == r) { myv = wv; myi = wi; }
        if (hi == wi && wi != SENT) ++p;        // real win only -> p <= PDEPTH
    }
    if (lane < TOPKK) { cV[wid * TOPKK + lane] = myv; cI[wid * TOPKK + lane] = myi; }
    __syncthreads();                            // the ONLY block barrier

    // ---- stage 2: wave 0 merges 52 candidates, scatters winners ----
    if (wid == 0) {
        float v = (lane < 4 * TOPKK) ? cV[lane] : -2.f;
        int   i = (lane < 4 * TOPKK) ? cI[lane] : SENT;
        int fi = SENT;
        for (int r = 0; r < TOPKK; ++r) {
            float wv = v; int wi = i;
#pragma unroll
            for (int s = 1; s < 64; s <<= 1) {
                float ov = __shfl_xor(wv, s, 64);
                int   oi = __shfl_xor(wi, s, 64);
                if (ov > wv || (ov == wv && oi < wi)) { wv = ov; wi = oi; }
            }
            if (lane == r) fi = wi;
            if (i == wi && wi != SENT) v = -2.f;  // consume real winner only
        }
        if (lane < TOPKK && fi >= 0 && fi < NAA) {
            float2 ap = ap2[fi];
            float din = fminf(fminf(ap.x - g.x, ap.y - g.y), fminf(g.z - ap.x, g.w - ap.y));
            if (din > EPSF)
                atomicAdd(&cnt[(size_t)b * NAA + fi], 1 + (j << 8));
        }
    }
}

// K2: per-anchor multi-gt resolution + per-row pos maxima. Grid (33, B):
// each block serves one batch; gt boxes / masks / atan(gw/gh) staged in LDS.
__global__ __launch_bounds__(256) void k2_resolve(
    const float* __restrict__ pd_scores,
    const float* __restrict__ pd_bboxes,
    const float* __restrict__ anc,
    const int*   __restrict__ gt_labels,
    const float* __restrict__ gt_bboxes,
    const float* __restrict__ mask_gt,
    const int* __restrict__ cnt,
    int* __restrict__ tgt, int* __restrict__ fgm, float* __restrict__ alv,
    int* __restrict__ pos)
{
    const int tid = threadIdx.x;
    const int b = blockIdx.y;
    const int a = blockIdx.x * 256 + tid;

    __shared__ float4 glds[NMX];
    __shared__ float  mlds[NMX];
    __shared__ float  galds[NMX];
    if (tid < NMX) {
        float4 gg = reinterpret_cast<const float4*>(gt_bboxes)[b * NMX + tid];
        glds[tid] = gg;
        mlds[tid] = mask_gt[b * NMX + tid];
        galds[tid] = atanf((gg.z - gg.x) / (gg.w - gg.y));
    }
    __syncthreads();
    if (a >= NAA) return;

    const int id = b * NAA + a;
    const int v = cnt[id];
    const int fg = v & 0xff;
    int tj = 0, f = 0;
    float al = 0.f;
    if (fg > 0) {
        f = 1;
        float2 ap = reinterpret_cast<const float2*>(anc)[a];
        float4 p = reinterpret_cast<const float4*>(pd_bboxes)[id];
        float pat = atanf((p.z - p.x) / (p.w - p.y));
        if (fg == 1) {
            tj = v >> 8;
        } else {
            float bv = -1.f; int bj = 0;
            for (int jj = 0; jj < NMX; ++jj) {
                float4 g = glds[jj];
                float din = fminf(fminf(ap.x - g.x, ap.y - g.y), fminf(g.z - ap.x, g.w - ap.y));
                float ov = 0.f;
                if (din > EPSF && mlds[jj] > 0.f) {
                    float c = ciou2(g.x, g.y, g.z, g.w, g.z - g.x, g.w - g.y, galds[jj],
                                    p.x, p.y, p.z, p.w, pat);
                    ov = fmaxf(c, 0.f);
                }
                if (ov > bv) { bv = ov; bj = jj; }   // strict > == first-argmax
            }
            tj = bj;
        }
        float4 g = glds[tj];
        float din = fminf(fminf(ap.x - g.x, ap.y - g.y), fminf(g.z - ap.x, g.w - ap.y));
        if (din > EPSF && mlds[tj] > 0.f) {
            float c = ciou2(g.x, g.y, g.z, g.w, g.z - g.x, g.w - g.y, galds[tj],
                            p.x, p.y, p.z, p.w, pat);
            float ov = fmaxf(c, 0.f);
            int gl = gt_labels[b * NMX + tj];
            float s = pd_scores[(size_t)id * NCC + gl];
            float o2 = ov * ov;
            al = s * (o2 * o2 * o2);
            if (ov > 0.f)
                atomicMax((unsigned int*)&pos[NROW + b * NMX + tj], __float_as_uint(ov));
        }
        if (al > 0.f)
            atomicMax((unsigned int*)&pos[b * NMX + tj], __float_as_uint(al));
    }
    tgt[id] = tj; fgm[id] = f; alv[id] = al;
}

// K3: all outputs, fully written; score region via coalesced float4 stores.
__global__ __launch_bounds__(256) void k3_out(
    const int* __restrict__ gt_labels,
    const float* __restrict__ gt_bboxes,
    const int* __restrict__ tgt, const int* __restrict__ fgm,
    const float* __restrict__ alv, const int* __restrict__ pos,
    float* __restrict__ o_lab, float* __restrict__ o_box, float* __restrict__ o_sc,
    float* __restrict__ o_fg, float* __restrict__ o_ti)
{
    const int id0 = blockIdx.x * 256;
    const int tid = threadIdx.x;
    const int id = id0 + tid;
    const int b = id / NAA;
    const int tj = tgt[id];
    const int f = fgm[id];
    int lab = gt_labels[b * NMX + tj]; lab = lab < 0 ? 0 : lab;
    float4 gb = reinterpret_cast<const float4*>(gt_bboxes)[b * NMX + tj];
    o_lab[id] = (float)lab;
    reinterpret_cast<float4*>(o_box)[id] = gb;
    o_fg[id] = f ? 1.f : 0.f;
    o_ti[id] = (float)tj;
    float val = 0.f;
    if (f) {
        float pa = __uint_as_float((unsigned int)pos[b * NMX + tj]);
        float po = __uint_as_float((unsigned int)pos[NROW + b * NMX + tj]);
        val = (alv[id] * po) / (pa + EPSF);
    }
    __shared__ int   s_lab[256];
    __shared__ float s_val[256];
    s_lab[tid] = lab;
    s_val[tid] = val;
    __syncthreads();
    float4* dst = reinterpret_cast<float4*>(o_sc + (size_t)id0 * NCC);
    const int NV = 256 * NCC / 4;   // 5120 float4s per block
#pragma unroll 4
    for (int i = tid; i < NV; i += 256) {
        int aa = i / (NCC / 4);
        int c0 = (i - aa * (NCC / 4)) * 4;
        int la = s_lab[aa];
        float vv = s_val[aa];
        float4 w;
        w.x = (la == c0 + 0) ? vv : 0.f;
        w.y = (la == c0 + 1) ? vv : 0.f;
        w.z = (la == c0 + 2) ? vv : 0.f;
        w.w = (la == c0 + 3) ? vv : 0.f;
        dst[i] = w;
    }
}

extern "C" void kernel_launch(void* const* d_in, const int* in_sizes, int n_in,
                              void* d_out, int out_size, void* d_ws, size_t ws_size,
                              hipStream_t stream)
{
    const float* pd_scores = (const float*)d_in[0];
    const float* pd_bboxes = (const float*)d_in[1];
    const float* anc       = (const float*)d_in[2];
    // d_in[3] rfields: unused by the reference
    const int*   gt_labels = (const int*)d_in[4];
    const float* gt_bboxes = (const float*)d_in[5];
    const float* mask_gt   = (const float*)d_in[6];

    const size_t nba = (size_t)NBA;
    int* cnt  = (int*)d_ws;                 // NBA
    int* pos  = cnt + nba;                  // 2*NROW (pos_al | pos_ov)
    int* tgt  = pos + 2 * NROW;             // NBA
    int* fgm  = tgt + nba;                  // NBA
    float* alv = (float*)(fgm + nba);       // NBA

    float* out = (float*)d_out;
    float* o_lab = out;                 // (B,NA)
    float* o_box = out + nba;           // (B,NA,4)
    float* o_sc  = out + nba * 5;       // (B,NA,NC)
    float* o_fg  = out + nba * 85;      // (B,NA)
    float* o_ti  = out + nba * 86;      // (B,NA)

    kz_zero<<<(NZI4 + 255) / 256, 256, 0, stream>>>((int4*)d_ws);
    ka_topk<<<NROW, 256, 0, stream>>>(pd_scores, pd_bboxes, anc, gt_labels,
                                      gt_bboxes, mask_gt, cnt);
    k2_resolve<<<dim3((NAA + 255) / 256, BB), 256, 0, stream>>>(
        pd_scores, pd_bboxes, anc, gt_labels, gt_bboxes, mask_gt, cnt,
        tgt, fgm, alv, pos);
    const int nblk = NBA / 256;   // 525, exact
    k3_out<<<nblk, 256, 0, stream>>>(gt_labels, gt_bboxes, tgt, fgm, alv, pos,
                                     o_lab, o_box, o_sc, o_fg, o_ti);
}